// Round 3
// baseline (480.551 us; speedup 1.0000x reference)
//
#include <hip/hip_runtime.h>

#define NN 50000
#define EE 800000
#define CH 128
#define NGR 64
#define NB 196        // ceil(NN/256)

// ---------------------------------------------------------------- CSR build
__global__ __launch_bounds__(256) void count_deg(const int* __restrict__ dst,
                                                 int* __restrict__ counts) {
  int e = blockIdx.x * 256 + threadIdx.x;
  if (e < EE) atomicAdd(&counts[dst[e]], 1);
}

__global__ __launch_bounds__(256) void scan_block_sums(const int* __restrict__ counts,
                                                       int* __restrict__ blockSums) {
  __shared__ int red[256];
  int t = threadIdx.x;
  int i = blockIdx.x * 256 + t;
  red[t] = (i < NN) ? counts[i] : 0;
  __syncthreads();
  for (int off = 128; off > 0; off >>= 1) {
    if (t < off) red[t] += red[t + off];
    __syncthreads();
  }
  if (t == 0) blockSums[blockIdx.x] = red[0];
}

__global__ __launch_bounds__(256) void scan_offsets(const int* __restrict__ blockSums,
                                                    int* __restrict__ blockOffs) {
  __shared__ int tmp[256];
  int t = threadIdx.x;
  int v = (t < NB) ? blockSums[t] : 0;
  tmp[t] = v;
  __syncthreads();
  for (int off = 1; off < 256; off <<= 1) {
    int add = (t >= off) ? tmp[t - off] : 0;
    __syncthreads();
    tmp[t] += add;
    __syncthreads();
  }
  if (t < NB) blockOffs[t] = tmp[t] - v;   // exclusive
}

__global__ __launch_bounds__(256) void scan_final(const int* __restrict__ counts,
                                                  const int* __restrict__ blockOffs,
                                                  int* __restrict__ rowptr,
                                                  int* __restrict__ fillptr,
                                                  float* __restrict__ dinv) {
  __shared__ int tmp[256];
  int t = threadIdx.x;
  int i = blockIdx.x * 256 + t;
  int v = (i < NN) ? counts[i] : 0;
  tmp[t] = v;
  __syncthreads();
  for (int off = 1; off < 256; off <<= 1) {
    int add = (t >= off) ? tmp[t - off] : 0;
    __syncthreads();
    tmp[t] += add;
    __syncthreads();
  }
  if (i < NN) {
    int ex = blockOffs[blockIdx.x] + tmp[t] - v;
    rowptr[i] = ex;
    fillptr[i] = ex;
    dinv[i] = rsqrtf((float)v + 1.0f);
  }
  if (i == 0) rowptr[NN] = EE;
}

__global__ __launch_bounds__(256) void fill_csr(const int* __restrict__ src,
                                                const int* __restrict__ dst,
                                                const float* __restrict__ dinv,
                                                int* __restrict__ fillptr,
                                                int* __restrict__ csrc,
                                                float* __restrict__ cnorm) {
  int e = blockIdx.x * 256 + threadIdx.x;
  if (e >= EE) return;
  int s = src[e], d = dst[e];
  int slot = atomicAdd(&fillptr[d], 1);
  csrc[slot] = s;
  cnorm[slot] = dinv[s] * dinv[d];
}

// ---------------------------------------------------------------- GEMM 50000x128 @ 128x128
// block = 256 threads, tile = 32 rows x 128 cols, K split in 2 halves of 64.
// LDS: sW 32KB + sX 16KB = 48KB -> 3 blocks/CU.
__global__ __launch_bounds__(256) void gemm128(const float* __restrict__ X,
                                               const float* __restrict__ W,
                                               float* __restrict__ H) {
  __shared__ float sW[64 * 128];
  __shared__ float sX[32 * 128];
  float4* sW4 = (float4*)sW;
  float4* sX4 = (float4*)sX;
  const float4* X4 = (const float4*)X;
  const float4* W4 = (const float4*)W;
  int t = threadIdx.x;
  int row0 = blockIdx.x * 32;
  int lane = t & 31;       // col group: cols lane*4 .. lane*4+3
  int rowg = t >> 5;       // row group: rows rowg*4 .. rowg*4+3

  // stage X tile (32 rows x 128 cols = 1024 float4)
  #pragma unroll
  for (int i = 0; i < 4; ++i) {
    int idx = t + 256 * i;
    int row = row0 + (idx >> 5);
    float4 v = make_float4(0.f, 0.f, 0.f, 0.f);
    if (row < NN) v = X4[(size_t)row * 32 + (idx & 31)];
    sX4[idx] = v;
  }

  float acc[4][4];
  #pragma unroll
  for (int r = 0; r < 4; ++r)
    #pragma unroll
    for (int c = 0; c < 4; ++c) acc[r][c] = 0.f;

  for (int kt = 0; kt < 2; ++kt) {
    __syncthreads();
    #pragma unroll
    for (int i = 0; i < 8; ++i) {
      int idx = t + 256 * i;              // 0..2047 covers 64 rows of W
      sW4[idx] = W4[kt * 2048 + idx];
    }
    __syncthreads();
    #pragma unroll
    for (int k4 = 0; k4 < 16; ++k4) {
      float4 xv[4];
      #pragma unroll
      for (int r = 0; r < 4; ++r)
        xv[r] = sX4[(rowg * 4 + r) * 32 + kt * 16 + k4];   // broadcast across 32 lanes
      #pragma unroll
      for (int kk = 0; kk < 4; ++kk) {
        float4 wv = sW4[(k4 * 4 + kk) * 32 + lane];
        #pragma unroll
        for (int r = 0; r < 4; ++r) {
          float xs = (kk == 0) ? xv[r].x : (kk == 1) ? xv[r].y : (kk == 2) ? xv[r].z : xv[r].w;
          acc[r][0] += xs * wv.x;
          acc[r][1] += xs * wv.y;
          acc[r][2] += xs * wv.z;
          acc[r][3] += xs * wv.w;
        }
      }
    }
  }

  #pragma unroll
  for (int r = 0; r < 4; ++r) {
    int row = row0 + rowg * 4 + r;
    if (row < NN)
      ((float4*)H)[(size_t)row * 32 + lane] =
          make_float4(acc[r][0], acc[r][1], acc[r][2], acc[r][3]);
  }
}

// ---------------------------------------------------------------- aggregation + self-loop + bias + tanh
// 32 lanes per node (4 channels each via float4); 8 nodes per 256-thread block.
__global__ __launch_bounds__(256) void gcn_agg(const float* __restrict__ H,
                                               const int* __restrict__ rowptr,
                                               const int* __restrict__ csrc,
                                               const float* __restrict__ cnorm,
                                               const float* __restrict__ dinv,
                                               const float* __restrict__ bias,
                                               float* __restrict__ out) {
  int nid = blockIdx.x * 8 + (threadIdx.x >> 5);
  if (nid >= NN) return;
  int lane = threadIdx.x & 31;
  const float4* H4 = (const float4*)H;
  float di = dinv[nid];
  float sw = di * di;
  float4 acc = H4[(size_t)nid * 32 + lane];
  acc.x *= sw; acc.y *= sw; acc.z *= sw; acc.w *= sw;
  int e0 = rowptr[nid], e1 = rowptr[nid + 1];
  for (int e = e0; e < e1; ++e) {
    int s = csrc[e];
    float wgt = cnorm[e];
    float4 v = H4[(size_t)s * 32 + lane];
    acc.x += v.x * wgt;
    acc.y += v.y * wgt;
    acc.z += v.z * wgt;
    acc.w += v.w * wgt;
  }
  float4 b = ((const float4*)bias)[lane];
  acc.x = tanhf(acc.x + b.x);
  acc.y = tanhf(acc.y + b.y);
  acc.z = tanhf(acc.z + b.z);
  acc.w = tanhf(acc.w + b.w);
  ((float4*)out)[(size_t)nid * 32 + lane] = acc;
}

// ---------------------------------------------------------------- final linear(128->6)+tanh + mean pool
// 4 threads per node; LDS per-graph accumulators, one flush per block.
__global__ __launch_bounds__(256) void linpool(const float* __restrict__ H,
                                               const float* __restrict__ Wl,
                                               const float* __restrict__ bl,
                                               const int* __restrict__ batch,
                                               float* __restrict__ gsum,
                                               int* __restrict__ gcnt) {
  __shared__ float sW[128 * 6];
  __shared__ float sSum[NGR * 6];
  __shared__ int sCnt[NGR];
  int t = threadIdx.x;
  for (int i = t; i < 768; i += 256) sW[i] = Wl[i];
  for (int i = t; i < NGR * 6; i += 256) sSum[i] = 0.f;
  if (t < NGR) sCnt[t] = 0;
  __syncthreads();

  int gid = blockIdx.x * 256 + t;
  int node = gid >> 2;
  int seg = gid & 3;          // each of 4 threads handles 32 k's
  float a0 = 0, a1 = 0, a2 = 0, a3 = 0, a4 = 0, a5 = 0;
  if (node < NN) {
    const float4* H4 = (const float4*)(H + (size_t)node * 128 + seg * 32);
    #pragma unroll
    for (int q = 0; q < 8; ++q) {
      float4 hv = H4[q];
      float hvv[4] = {hv.x, hv.y, hv.z, hv.w};
      int kbase = seg * 32 + q * 4;
      #pragma unroll
      for (int kk = 0; kk < 4; ++kk) {
        float hx = hvv[kk];
        const float* wr = &sW[(kbase + kk) * 6];
        a0 += hx * wr[0]; a1 += hx * wr[1]; a2 += hx * wr[2];
        a3 += hx * wr[3]; a4 += hx * wr[4]; a5 += hx * wr[5];
      }
    }
  }
  // reduce across the 4 lanes of the node
  a0 += __shfl_xor(a0, 1); a0 += __shfl_xor(a0, 2);
  a1 += __shfl_xor(a1, 1); a1 += __shfl_xor(a1, 2);
  a2 += __shfl_xor(a2, 1); a2 += __shfl_xor(a2, 2);
  a3 += __shfl_xor(a3, 1); a3 += __shfl_xor(a3, 2);
  a4 += __shfl_xor(a4, 1); a4 += __shfl_xor(a4, 2);
  a5 += __shfl_xor(a5, 1); a5 += __shfl_xor(a5, 2);
  if (node < NN && seg == 0) {
    int g = batch[node];
    atomicAdd(&sSum[g * 6 + 0], tanhf(a0 + bl[0]));
    atomicAdd(&sSum[g * 6 + 1], tanhf(a1 + bl[1]));
    atomicAdd(&sSum[g * 6 + 2], tanhf(a2 + bl[2]));
    atomicAdd(&sSum[g * 6 + 3], tanhf(a3 + bl[3]));
    atomicAdd(&sSum[g * 6 + 4], tanhf(a4 + bl[4]));
    atomicAdd(&sSum[g * 6 + 5], tanhf(a5 + bl[5]));
    atomicAdd(&sCnt[g], 1);
  }
  __syncthreads();
  for (int i = t; i < NGR * 6; i += 256) {
    int g = i / 6;
    if (sCnt[g] > 0) atomicAdd(&gsum[i], sSum[i]);
  }
  if (t < NGR && sCnt[t] > 0) atomicAdd(&gcnt[t], sCnt[t]);
}

__global__ void finalize(const float* __restrict__ gsum, const int* __restrict__ gcnt,
                         float* __restrict__ out) {
  int i = threadIdx.x;
  if (i < NGR * 6) {
    int g = i / 6;
    float c = (float)max(gcnt[g], 1);
    out[i] = gsum[i] / c;
  }
}

// ---------------------------------------------------------------- launch
extern "C" void kernel_launch(void* const* d_in, const int* in_sizes, int n_in,
                              void* d_out, int out_size, void* d_ws, size_t ws_size,
                              hipStream_t stream) {
  const float* x  = (const float*)d_in[0];
  const int*   ei = (const int*)d_in[1];     // JAX x64 disabled -> int32
  const int*   batch = (const int*)d_in[2];
  const float* W0 = (const float*)d_in[3];
  const float* b0 = (const float*)d_in[4];
  const float* W1 = (const float*)d_in[5];
  const float* b1 = (const float*)d_in[6];
  const float* W2 = (const float*)d_in[7];
  const float* b2 = (const float*)d_in[8];
  const float* Wl = (const float*)d_in[9];
  const float* bl = (const float*)d_in[10];
  float* out = (float*)d_out;

  const int* src = ei;
  const int* dst = ei + EE;

  char* w = (char*)d_ws;
  auto alloc = [&](size_t bytes) {
    void* p = (void*)w;
    w += (bytes + 255) & ~(size_t)255;
    return p;
  };
  float* bufA   = (float*)alloc((size_t)NN * CH * 4);
  float* bufB   = (float*)alloc((size_t)NN * CH * 4);
  int*   counts = (int*)alloc((size_t)NN * 4);
  int*   rowptr = (int*)alloc((size_t)(NN + 1) * 4);
  int*   fillptr= (int*)alloc((size_t)NN * 4);
  float* dinv   = (float*)alloc((size_t)NN * 4);
  int*   csrc   = (int*)alloc((size_t)EE * 4);
  float* cnorm  = (float*)alloc((size_t)EE * 4);
  int*   blockSums = (int*)alloc(256 * 4);
  int*   blockOffs = (int*)alloc(256 * 4);
  float* gsum   = (float*)alloc((NGR * 6 + NGR) * 4);
  int*   gcnt   = (int*)(gsum + NGR * 6);

  hipMemsetAsync(counts, 0, (size_t)NN * 4, stream);
  hipMemsetAsync(gsum, 0, (NGR * 6 + NGR) * 4, stream);

  // CSR build (reused for all 3 layers)
  count_deg<<<(EE + 255) / 256, 256, 0, stream>>>(dst, counts);
  scan_block_sums<<<NB, 256, 0, stream>>>(counts, blockSums);
  scan_offsets<<<1, 256, 0, stream>>>(blockSums, blockOffs);
  scan_final<<<NB, 256, 0, stream>>>(counts, blockOffs, rowptr, fillptr, dinv);
  fill_csr<<<(EE + 255) / 256, 256, 0, stream>>>(src, dst, dinv, fillptr, csrc, cnorm);

  const int gemmGrid = (NN + 31) / 32;
  const int aggGrid  = (NN + 7) / 8;

  // layer 0: x -> bufA (h) -> bufB (act)
  gemm128<<<gemmGrid, 256, 0, stream>>>(x, W0, bufA);
  gcn_agg<<<aggGrid, 256, 0, stream>>>(bufA, rowptr, csrc, cnorm, dinv, b0, bufB);
  // layer 1
  gemm128<<<gemmGrid, 256, 0, stream>>>(bufB, W1, bufA);
  gcn_agg<<<aggGrid, 256, 0, stream>>>(bufA, rowptr, csrc, cnorm, dinv, b1, bufB);
  // layer 2
  gemm128<<<gemmGrid, 256, 0, stream>>>(bufB, W2, bufA);
  gcn_agg<<<aggGrid, 256, 0, stream>>>(bufA, rowptr, csrc, cnorm, dinv, b2, bufB);

  // final linear + tanh + mean pool
  linpool<<<(NN * 4 + 255) / 256, 256, 0, stream>>>(bufB, Wl, bl, batch, gsum, gcnt);
  finalize<<<1, NGR * 6, 0, stream>>>(gsum, gcnt, out);
}

// Round 4
// 461.846 us; speedup vs baseline: 1.0405x; 1.0405x over previous
//
#include <hip/hip_runtime.h>

#define NN 50000
#define EE 800000
#define CH 128
#define NGR 64
#define NB 196        // ceil(NN/256)

// ---------------------------------------------------------------- CSR build
__global__ __launch_bounds__(256) void count_deg(const int* __restrict__ dst,
                                                 int* __restrict__ counts) {
  int e = blockIdx.x * 256 + threadIdx.x;
  if (e < EE) atomicAdd(&counts[dst[e]], 1);
}

__global__ __launch_bounds__(256) void scan_block_sums(const int* __restrict__ counts,
                                                       int* __restrict__ blockSums) {
  __shared__ int red[256];
  int t = threadIdx.x;
  int i = blockIdx.x * 256 + t;
  red[t] = (i < NN) ? counts[i] : 0;
  __syncthreads();
  for (int off = 128; off > 0; off >>= 1) {
    if (t < off) red[t] += red[t + off];
    __syncthreads();
  }
  if (t == 0) blockSums[blockIdx.x] = red[0];
}

__global__ __launch_bounds__(256) void scan_offsets(const int* __restrict__ blockSums,
                                                    int* __restrict__ blockOffs) {
  __shared__ int tmp[256];
  int t = threadIdx.x;
  int v = (t < NB) ? blockSums[t] : 0;
  tmp[t] = v;
  __syncthreads();
  for (int off = 1; off < 256; off <<= 1) {
    int add = (t >= off) ? tmp[t - off] : 0;
    __syncthreads();
    tmp[t] += add;
    __syncthreads();
  }
  if (t < NB) blockOffs[t] = tmp[t] - v;   // exclusive
}

__global__ __launch_bounds__(256) void scan_final(const int* __restrict__ counts,
                                                  const int* __restrict__ blockOffs,
                                                  int* __restrict__ rowptr,
                                                  int* __restrict__ fillptr,
                                                  float* __restrict__ dinv) {
  __shared__ int tmp[256];
  int t = threadIdx.x;
  int i = blockIdx.x * 256 + t;
  int v = (i < NN) ? counts[i] : 0;
  tmp[t] = v;
  __syncthreads();
  for (int off = 1; off < 256; off <<= 1) {
    int add = (t >= off) ? tmp[t - off] : 0;
    __syncthreads();
    tmp[t] += add;
    __syncthreads();
  }
  if (i < NN) {
    int ex = blockOffs[blockIdx.x] + tmp[t] - v;
    rowptr[i] = ex;
    fillptr[i] = ex;
    dinv[i] = rsqrtf((float)v + 1.0f);
  }
  if (i == 0) rowptr[NN] = EE;
}

// packed edge record: .x = src node, .y = bitcast(norm)
__global__ __launch_bounds__(256) void fill_csr(const int* __restrict__ src,
                                                const int* __restrict__ dst,
                                                const float* __restrict__ dinv,
                                                int* __restrict__ fillptr,
                                                int2* __restrict__ edges) {
  int e = blockIdx.x * 256 + threadIdx.x;
  if (e >= EE) return;
  int s = src[e], d = dst[e];
  int slot = atomicAdd(&fillptr[d], 1);
  edges[slot] = make_int2(s, __float_as_int(dinv[s] * dinv[d]));
}

// ---------------------------------------------------------------- GEMM 50000x128 @ 128x128
// block = 256 threads, tile = 32 rows x 128 cols, K split in 2 halves of 64.
// LDS: sW 32KB + sX 16KB = 48KB -> 3 blocks/CU.
__global__ __launch_bounds__(256) void gemm128(const float* __restrict__ X,
                                               const float* __restrict__ W,
                                               float* __restrict__ H) {
  __shared__ float sW[64 * 128];
  __shared__ float sX[32 * 128];
  float4* sW4 = (float4*)sW;
  float4* sX4 = (float4*)sX;
  const float4* X4 = (const float4*)X;
  const float4* W4 = (const float4*)W;
  int t = threadIdx.x;
  int row0 = blockIdx.x * 32;
  int lane = t & 31;       // col group: cols lane*4 .. lane*4+3
  int rowg = t >> 5;       // row group: rows rowg*4 .. rowg*4+3

  // stage X tile (32 rows x 128 cols = 1024 float4)
  #pragma unroll
  for (int i = 0; i < 4; ++i) {
    int idx = t + 256 * i;
    int row = row0 + (idx >> 5);
    float4 v = make_float4(0.f, 0.f, 0.f, 0.f);
    if (row < NN) v = X4[(size_t)row * 32 + (idx & 31)];
    sX4[idx] = v;
  }

  float acc[4][4];
  #pragma unroll
  for (int r = 0; r < 4; ++r)
    #pragma unroll
    for (int c = 0; c < 4; ++c) acc[r][c] = 0.f;

  for (int kt = 0; kt < 2; ++kt) {
    __syncthreads();
    #pragma unroll
    for (int i = 0; i < 8; ++i) {
      int idx = t + 256 * i;              // 0..2047 covers 64 rows of W
      sW4[idx] = W4[kt * 2048 + idx];
    }
    __syncthreads();
    #pragma unroll
    for (int k4 = 0; k4 < 16; ++k4) {
      float4 xv[4];
      #pragma unroll
      for (int r = 0; r < 4; ++r)
        xv[r] = sX4[(rowg * 4 + r) * 32 + kt * 16 + k4];   // broadcast across 32 lanes
      #pragma unroll
      for (int kk = 0; kk < 4; ++kk) {
        float4 wv = sW4[(k4 * 4 + kk) * 32 + lane];
        #pragma unroll
        for (int r = 0; r < 4; ++r) {
          float xs = (kk == 0) ? xv[r].x : (kk == 1) ? xv[r].y : (kk == 2) ? xv[r].z : xv[r].w;
          acc[r][0] += xs * wv.x;
          acc[r][1] += xs * wv.y;
          acc[r][2] += xs * wv.z;
          acc[r][3] += xs * wv.w;
        }
      }
    }
  }

  #pragma unroll
  for (int r = 0; r < 4; ++r) {
    int row = row0 + rowg * 4 + r;
    if (row < NN)
      ((float4*)H)[(size_t)row * 32 + lane] =
          make_float4(acc[r][0], acc[r][1], acc[r][2], acc[r][3]);
  }
}

// ---------------------------------------------------------------- aggregation + self-loop + bias + tanh
// 32 lanes per node (4 channels each via float4); 8 nodes per 256-thread block.
// Edge loop: batches of 8 with predicated loads -> 8 gathers in flight (MLP).
__global__ __launch_bounds__(256) void gcn_agg(const float* __restrict__ H,
                                               const int* __restrict__ rowptr,
                                               const int2* __restrict__ edges,
                                               const float* __restrict__ dinv,
                                               const float* __restrict__ bias,
                                               float* __restrict__ out) {
  int nid = blockIdx.x * 8 + (threadIdx.x >> 5);
  if (nid >= NN) return;
  int lane = threadIdx.x & 31;
  const float4* H4 = (const float4*)H;
  float di = dinv[nid];
  float sw = di * di;
  float4 self = H4[(size_t)nid * 32 + lane];
  float ax = self.x * sw, ay = self.y * sw, az = self.z * sw, aw = self.w * sw;

  int e0 = rowptr[nid], e1 = rowptr[nid + 1];
  for (int e = e0; e < e1; e += 8) {
    int2 ed[8];
    #pragma unroll
    for (int u = 0; u < 8; ++u) {
      // masked edges read record 0 with weight 0 -> harmless gather of node 0
      ed[u] = (e + u < e1) ? edges[e + u] : make_int2(0, 0);
    }
    float4 v[8];
    #pragma unroll
    for (int u = 0; u < 8; ++u)
      v[u] = H4[(size_t)ed[u].x * 32 + lane];
    #pragma unroll
    for (int u = 0; u < 8; ++u) {
      float wgt = __int_as_float(ed[u].y);
      ax += v[u].x * wgt;
      ay += v[u].y * wgt;
      az += v[u].z * wgt;
      aw += v[u].w * wgt;
    }
  }

  float4 b = ((const float4*)bias)[lane];
  float4 r;
  r.x = tanhf(ax + b.x);
  r.y = tanhf(ay + b.y);
  r.z = tanhf(az + b.z);
  r.w = tanhf(aw + b.w);
  ((float4*)out)[(size_t)nid * 32 + lane] = r;
}

// ---------------------------------------------------------------- final linear(128->6)+tanh + mean pool
// 4 threads per node; LDS per-graph accumulators, one flush per block.
__global__ __launch_bounds__(256) void linpool(const float* __restrict__ H,
                                               const float* __restrict__ Wl,
                                               const float* __restrict__ bl,
                                               const int* __restrict__ batch,
                                               float* __restrict__ gsum,
                                               int* __restrict__ gcnt) {
  __shared__ float sW[128 * 6];
  __shared__ float sSum[NGR * 6];
  __shared__ int sCnt[NGR];
  int t = threadIdx.x;
  for (int i = t; i < 768; i += 256) sW[i] = Wl[i];
  for (int i = t; i < NGR * 6; i += 256) sSum[i] = 0.f;
  if (t < NGR) sCnt[t] = 0;
  __syncthreads();

  int gid = blockIdx.x * 256 + t;
  int node = gid >> 2;
  int seg = gid & 3;          // each of 4 threads handles 32 k's
  float a0 = 0, a1 = 0, a2 = 0, a3 = 0, a4 = 0, a5 = 0;
  if (node < NN) {
    const float4* H4 = (const float4*)(H + (size_t)node * 128 + seg * 32);
    #pragma unroll
    for (int q = 0; q < 8; ++q) {
      float4 hv = H4[q];
      float hvv[4] = {hv.x, hv.y, hv.z, hv.w};
      int kbase = seg * 32 + q * 4;
      #pragma unroll
      for (int kk = 0; kk < 4; ++kk) {
        float hx = hvv[kk];
        const float* wr = &sW[(kbase + kk) * 6];
        a0 += hx * wr[0]; a1 += hx * wr[1]; a2 += hx * wr[2];
        a3 += hx * wr[3]; a4 += hx * wr[4]; a5 += hx * wr[5];
      }
    }
  }
  // reduce across the 4 lanes of the node
  a0 += __shfl_xor(a0, 1); a0 += __shfl_xor(a0, 2);
  a1 += __shfl_xor(a1, 1); a1 += __shfl_xor(a1, 2);
  a2 += __shfl_xor(a2, 1); a2 += __shfl_xor(a2, 2);
  a3 += __shfl_xor(a3, 1); a3 += __shfl_xor(a3, 2);
  a4 += __shfl_xor(a4, 1); a4 += __shfl_xor(a4, 2);
  a5 += __shfl_xor(a5, 1); a5 += __shfl_xor(a5, 2);
  if (node < NN && seg == 0) {
    int g = batch[node];
    atomicAdd(&sSum[g * 6 + 0], tanhf(a0 + bl[0]));
    atomicAdd(&sSum[g * 6 + 1], tanhf(a1 + bl[1]));
    atomicAdd(&sSum[g * 6 + 2], tanhf(a2 + bl[2]));
    atomicAdd(&sSum[g * 6 + 3], tanhf(a3 + bl[3]));
    atomicAdd(&sSum[g * 6 + 4], tanhf(a4 + bl[4]));
    atomicAdd(&sSum[g * 6 + 5], tanhf(a5 + bl[5]));
    atomicAdd(&sCnt[g], 1);
  }
  __syncthreads();
  for (int i = t; i < NGR * 6; i += 256) {
    int g = i / 6;
    if (sCnt[g] > 0) atomicAdd(&gsum[i], sSum[i]);
  }
  if (t < NGR && sCnt[t] > 0) atomicAdd(&gcnt[t], sCnt[t]);
}

__global__ void finalize(const float* __restrict__ gsum, const int* __restrict__ gcnt,
                         float* __restrict__ out) {
  int i = threadIdx.x;
  if (i < NGR * 6) {
    int g = i / 6;
    float c = (float)max(gcnt[g], 1);
    out[i] = gsum[i] / c;
  }
}

// ---------------------------------------------------------------- launch
extern "C" void kernel_launch(void* const* d_in, const int* in_sizes, int n_in,
                              void* d_out, int out_size, void* d_ws, size_t ws_size,
                              hipStream_t stream) {
  const float* x  = (const float*)d_in[0];
  const int*   ei = (const int*)d_in[1];     // JAX x64 disabled -> int32
  const int*   batch = (const int*)d_in[2];
  const float* W0 = (const float*)d_in[3];
  const float* b0 = (const float*)d_in[4];
  const float* W1 = (const float*)d_in[5];
  const float* b1 = (const float*)d_in[6];
  const float* W2 = (const float*)d_in[7];
  const float* b2 = (const float*)d_in[8];
  const float* Wl = (const float*)d_in[9];
  const float* bl = (const float*)d_in[10];
  float* out = (float*)d_out;

  const int* src = ei;
  const int* dst = ei + EE;

  char* w = (char*)d_ws;
  auto alloc = [&](size_t bytes) {
    void* p = (void*)w;
    w += (bytes + 255) & ~(size_t)255;
    return p;
  };
  float* bufA   = (float*)alloc((size_t)NN * CH * 4);
  float* bufB   = (float*)alloc((size_t)NN * CH * 4);
  int*   counts = (int*)alloc((size_t)NN * 4);
  int*   rowptr = (int*)alloc((size_t)(NN + 1) * 4);
  int*   fillptr= (int*)alloc((size_t)NN * 4);
  float* dinv   = (float*)alloc((size_t)NN * 4);
  int2*  edges  = (int2*)alloc((size_t)EE * 8);
  int*   blockSums = (int*)alloc(256 * 4);
  int*   blockOffs = (int*)alloc(256 * 4);
  float* gsum   = (float*)alloc((NGR * 6 + NGR) * 4);
  int*   gcnt   = (int*)(gsum + NGR * 6);

  hipMemsetAsync(counts, 0, (size_t)NN * 4, stream);
  hipMemsetAsync(gsum, 0, (NGR * 6 + NGR) * 4, stream);

  // CSR build (reused for all 3 layers)
  count_deg<<<(EE + 255) / 256, 256, 0, stream>>>(dst, counts);
  scan_block_sums<<<NB, 256, 0, stream>>>(counts, blockSums);
  scan_offsets<<<1, 256, 0, stream>>>(blockSums, blockOffs);
  scan_final<<<NB, 256, 0, stream>>>(counts, blockOffs, rowptr, fillptr, dinv);
  fill_csr<<<(EE + 255) / 256, 256, 0, stream>>>(src, dst, dinv, fillptr, edges);

  const int gemmGrid = (NN + 31) / 32;
  const int aggGrid  = (NN + 7) / 8;

  // layer 0: x -> bufA (h) -> bufB (act)
  gemm128<<<gemmGrid, 256, 0, stream>>>(x, W0, bufA);
  gcn_agg<<<aggGrid, 256, 0, stream>>>(bufA, rowptr, edges, dinv, b0, bufB);
  // layer 1
  gemm128<<<gemmGrid, 256, 0, stream>>>(bufB, W1, bufA);
  gcn_agg<<<aggGrid, 256, 0, stream>>>(bufA, rowptr, edges, dinv, b1, bufB);
  // layer 2
  gemm128<<<gemmGrid, 256, 0, stream>>>(bufB, W2, bufA);
  gcn_agg<<<aggGrid, 256, 0, stream>>>(bufA, rowptr, edges, dinv, b2, bufB);

  // final linear + tanh + mean pool
  linpool<<<(NN * 4 + 255) / 256, 256, 0, stream>>>(bufB, Wl, bl, batch, gsum, gcnt);
  finalize<<<1, NGR * 6, 0, stream>>>(gsum, gcnt, out);
}

// Round 7
// 447.634 us; speedup vs baseline: 1.0735x; 1.0317x over previous
//
#include <hip/hip_runtime.h>

#define NN 50000
#define EE 800000
#define CH 128
#define NGR 64
#define NB 196        // ceil(NN/256)

// ---------------------------------------------------------------- CSR build
__global__ __launch_bounds__(256) void count_deg(const int* __restrict__ dst,
                                                 int* __restrict__ counts) {
  int e = blockIdx.x * 256 + threadIdx.x;
  if (e < EE) atomicAdd(&counts[dst[e]], 1);
}

__global__ __launch_bounds__(256) void scan_block_sums(const int* __restrict__ counts,
                                                       int* __restrict__ blockSums) {
  __shared__ int red[256];
  int t = threadIdx.x;
  int i = blockIdx.x * 256 + t;
  red[t] = (i < NN) ? counts[i] : 0;
  __syncthreads();
  for (int off = 128; off > 0; off >>= 1) {
    if (t < off) red[t] += red[t + off];
    __syncthreads();
  }
  if (t == 0) blockSums[blockIdx.x] = red[0];
}

__global__ __launch_bounds__(256) void scan_offsets(const int* __restrict__ blockSums,
                                                    int* __restrict__ blockOffs) {
  __shared__ int tmp[256];
  int t = threadIdx.x;
  int v = (t < NB) ? blockSums[t] : 0;
  tmp[t] = v;
  __syncthreads();
  for (int off = 1; off < 256; off <<= 1) {
    int add = (t >= off) ? tmp[t - off] : 0;
    __syncthreads();
    tmp[t] += add;
    __syncthreads();
  }
  if (t < NB) blockOffs[t] = tmp[t] - v;   // exclusive
}

__global__ __launch_bounds__(256) void scan_final(const int* __restrict__ counts,
                                                  const int* __restrict__ blockOffs,
                                                  int* __restrict__ rowptr,
                                                  int* __restrict__ fillptr,
                                                  float* __restrict__ dinv) {
  __shared__ int tmp[256];
  int t = threadIdx.x;
  int i = blockIdx.x * 256 + t;
  int v = (i < NN) ? counts[i] : 0;
  tmp[t] = v;
  __syncthreads();
  for (int off = 1; off < 256; off <<= 1) {
    int add = (t >= off) ? tmp[t - off] : 0;
    __syncthreads();
    tmp[t] += add;
    __syncthreads();
  }
  if (i < NN) {
    int ex = blockOffs[blockIdx.x] + tmp[t] - v;
    rowptr[i] = ex;
    fillptr[i] = ex;
    dinv[i] = rsqrtf((float)v + 1.0f);
  }
  if (i == 0) rowptr[NN] = EE;
}

// packed edge record: .x = src node, .y = bitcast(norm)
__global__ __launch_bounds__(256) void fill_csr(const int* __restrict__ src,
                                                const int* __restrict__ dst,
                                                const float* __restrict__ dinv,
                                                int* __restrict__ fillptr,
                                                int2* __restrict__ edges) {
  int e = blockIdx.x * 256 + threadIdx.x;
  if (e >= EE) return;
  int s = src[e], d = dst[e];
  int slot = atomicAdd(&fillptr[d], 1);
  edges[slot] = make_int2(s, __float_as_int(dinv[s] * dinv[d]));
}

// ---------------------------------------------------------------- GEMM 50000x128 @ 128x128
// block = 256 threads, tile = 32 rows x 128 cols, K split in 2 halves of 64.
// LDS: sW 32KB + sX 16KB = 48KB -> 3 blocks/CU.
__global__ __launch_bounds__(256) void gemm128(const float* __restrict__ X,
                                               const float* __restrict__ W,
                                               float* __restrict__ H) {
  __shared__ float sW[64 * 128];
  __shared__ float sX[32 * 128];
  float4* sW4 = (float4*)sW;
  float4* sX4 = (float4*)sX;
  const float4* X4 = (const float4*)X;
  const float4* W4 = (const float4*)W;
  int t = threadIdx.x;
  int row0 = blockIdx.x * 32;
  int lane = t & 31;       // col group: cols lane*4 .. lane*4+3
  int rowg = t >> 5;       // row group: rows rowg*4 .. rowg*4+3

  // stage X tile (32 rows x 128 cols = 1024 float4)
  #pragma unroll
  for (int i = 0; i < 4; ++i) {
    int idx = t + 256 * i;
    int row = row0 + (idx >> 5);
    float4 v = make_float4(0.f, 0.f, 0.f, 0.f);
    if (row < NN) v = X4[(size_t)row * 32 + (idx & 31)];
    sX4[idx] = v;
  }

  float acc[4][4];
  #pragma unroll
  for (int r = 0; r < 4; ++r)
    #pragma unroll
    for (int c = 0; c < 4; ++c) acc[r][c] = 0.f;

  for (int kt = 0; kt < 2; ++kt) {
    __syncthreads();
    #pragma unroll
    for (int i = 0; i < 8; ++i) {
      int idx = t + 256 * i;              // 0..2047 covers 64 rows of W
      sW4[idx] = W4[kt * 2048 + idx];
    }
    __syncthreads();
    #pragma unroll
    for (int k4 = 0; k4 < 16; ++k4) {
      float4 xv[4];
      #pragma unroll
      for (int r = 0; r < 4; ++r)
        xv[r] = sX4[(rowg * 4 + r) * 32 + kt * 16 + k4];   // broadcast across 32 lanes
      #pragma unroll
      for (int kk = 0; kk < 4; ++kk) {
        float4 wv = sW4[(k4 * 4 + kk) * 32 + lane];
        #pragma unroll
        for (int r = 0; r < 4; ++r) {
          float xs = (kk == 0) ? xv[r].x : (kk == 1) ? xv[r].y : (kk == 2) ? xv[r].z : xv[r].w;
          acc[r][0] += xs * wv.x;
          acc[r][1] += xs * wv.y;
          acc[r][2] += xs * wv.z;
          acc[r][3] += xs * wv.w;
        }
      }
    }
  }

  #pragma unroll
  for (int r = 0; r < 4; ++r) {
    int row = row0 + rowg * 4 + r;
    if (row < NN)
      ((float4*)H)[(size_t)row * 32 + lane] =
          make_float4(acc[r][0], acc[r][1], acc[r][2], acc[r][3]);
  }
}

// ---------------------------------------------------------------- aggregation + self-loop + bias + tanh
// 1 wave per node: 64 lanes x float2. Edge records loaded cooperatively
// (lane l reads edges[e0+l], one dwordx2 for up to 64 records), then
// readlane-broadcast -> SGPR-based gathers, all independent, 8-deep unroll.
__global__ __launch_bounds__(256) void gcn_agg(const float* __restrict__ H,
                                               const int* __restrict__ rowptr,
                                               const int2* __restrict__ edges,
                                               const float* __restrict__ dinv,
                                               const float* __restrict__ bias,
                                               float* __restrict__ out) {
  int nid = blockIdx.x * 4 + (threadIdx.x >> 6);
  if (nid >= NN) return;
  int lane = threadIdx.x & 63;
  const float2* H2 = (const float2*)H;          // row stride = 64 float2
  float di = dinv[nid];
  float sw = di * di;
  float2 self = H2[(size_t)nid * 64 + lane];
  float ax = self.x * sw, ay = self.y * sw;

  int e0 = rowptr[nid], e1 = rowptr[nid + 1];
  for (int c = e0; c < e1; c += 64) {
    // cooperative edge-record load; inactive lanes get {src=0, w=0}
    int2 rec = (c + lane < e1) ? edges[c + lane] : make_int2(0, 0);
    int cnt = e1 - c; if (cnt > 64) cnt = 64;
    int cend = (cnt + 7) & ~7;                  // round to unroll width
    for (int u = 0; u < cend; u += 8) {
      float2 v[8];
      float wg[8];
      #pragma unroll
      for (int q = 0; q < 8; ++q) {
        int s  = __builtin_amdgcn_readlane(rec.x, u + q);   // SGPR src id
        wg[q]  = __int_as_float(__builtin_amdgcn_readlane(rec.y, u + q));
        v[q]   = H2[(size_t)s * 64 + lane];     // saddr + lane offset gather
      }
      #pragma unroll
      for (int q = 0; q < 8; ++q) {
        ax += v[q].x * wg[q];
        ay += v[q].y * wg[q];
      }
    }
  }

  float2 b = ((const float2*)bias)[lane];
  float2 r;
  r.x = tanhf(ax + b.x);
  r.y = tanhf(ay + b.y);
  ((float2*)out)[(size_t)nid * 64 + lane] = r;
}

// ---------------------------------------------------------------- final linear(128->6)+tanh + mean pool
// 4 threads per node; LDS per-graph accumulators, one flush per block.
__global__ __launch_bounds__(256) void linpool(const float* __restrict__ H,
                                               const float* __restrict__ Wl,
                                               const float* __restrict__ bl,
                                               const int* __restrict__ batch,
                                               float* __restrict__ gsum,
                                               int* __restrict__ gcnt) {
  __shared__ float sW[128 * 6];
  __shared__ float sSum[NGR * 6];
  __shared__ int sCnt[NGR];
  int t = threadIdx.x;
  for (int i = t; i < 768; i += 256) sW[i] = Wl[i];
  for (int i = t; i < NGR * 6; i += 256) sSum[i] = 0.f;
  if (t < NGR) sCnt[t] = 0;
  __syncthreads();

  int gid = blockIdx.x * 256 + t;
  int node = gid >> 2;
  int seg = gid & 3;          // each of 4 threads handles 32 k's
  float a0 = 0, a1 = 0, a2 = 0, a3 = 0, a4 = 0, a5 = 0;
  if (node < NN) {
    const float4* H4 = (const float4*)(H + (size_t)node * 128 + seg * 32);
    #pragma unroll
    for (int q = 0; q < 8; ++q) {
      float4 hv = H4[q];
      float hvv[4] = {hv.x, hv.y, hv.z, hv.w};
      int kbase = seg * 32 + q * 4;
      #pragma unroll
      for (int kk = 0; kk < 4; ++kk) {
        float hx = hvv[kk];
        const float* wr = &sW[(kbase + kk) * 6];
        a0 += hx * wr[0]; a1 += hx * wr[1]; a2 += hx * wr[2];
        a3 += hx * wr[3]; a4 += hx * wr[4]; a5 += hx * wr[5];
      }
    }
  }
  // reduce across the 4 lanes of the node
  a0 += __shfl_xor(a0, 1); a0 += __shfl_xor(a0, 2);
  a1 += __shfl_xor(a1, 1); a1 += __shfl_xor(a1, 2);
  a2 += __shfl_xor(a2, 1); a2 += __shfl_xor(a2, 2);
  a3 += __shfl_xor(a3, 1); a3 += __shfl_xor(a3, 2);
  a4 += __shfl_xor(a4, 1); a4 += __shfl_xor(a4, 2);
  a5 += __shfl_xor(a5, 1); a5 += __shfl_xor(a5, 2);
  if (node < NN && seg == 0) {
    int g = batch[node];
    atomicAdd(&sSum[g * 6 + 0], tanhf(a0 + bl[0]));
    atomicAdd(&sSum[g * 6 + 1], tanhf(a1 + bl[1]));
    atomicAdd(&sSum[g * 6 + 2], tanhf(a2 + bl[2]));
    atomicAdd(&sSum[g * 6 + 3], tanhf(a3 + bl[3]));
    atomicAdd(&sSum[g * 6 + 4], tanhf(a4 + bl[4]));
    atomicAdd(&sSum[g * 6 + 5], tanhf(a5 + bl[5]));
    atomicAdd(&sCnt[g], 1);
  }
  __syncthreads();
  for (int i = t; i < NGR * 6; i += 256) {
    int g = i / 6;
    if (sCnt[g] > 0) atomicAdd(&gsum[i], sSum[i]);
  }
  if (t < NGR && sCnt[t] > 0) atomicAdd(&gcnt[t], sCnt[t]);
}

__global__ void finalize(const float* __restrict__ gsum, const int* __restrict__ gcnt,
                         float* __restrict__ out) {
  int i = threadIdx.x;
  if (i < NGR * 6) {
    int g = i / 6;
    float c = (float)max(gcnt[g], 1);
    out[i] = gsum[i] / c;
  }
}

// ---------------------------------------------------------------- launch
extern "C" void kernel_launch(void* const* d_in, const int* in_sizes, int n_in,
                              void* d_out, int out_size, void* d_ws, size_t ws_size,
                              hipStream_t stream) {
  const float* x  = (const float*)d_in[0];
  const int*   ei = (const int*)d_in[1];     // JAX x64 disabled -> int32
  const int*   batch = (const int*)d_in[2];
  const float* W0 = (const float*)d_in[3];
  const float* b0 = (const float*)d_in[4];
  const float* W1 = (const float*)d_in[5];
  const float* b1 = (const float*)d_in[6];
  const float* W2 = (const float*)d_in[7];
  const float* b2 = (const float*)d_in[8];
  const float* Wl = (const float*)d_in[9];
  const float* bl = (const float*)d_in[10];
  float* out = (float*)d_out;

  const int* src = ei;
  const int* dst = ei + EE;

  char* w = (char*)d_ws;
  auto alloc = [&](size_t bytes) {
    void* p = (void*)w;
    w += (bytes + 255) & ~(size_t)255;
    return p;
  };
  float* bufA   = (float*)alloc((size_t)NN * CH * 4);
  float* bufB   = (float*)alloc((size_t)NN * CH * 4);
  int*   counts = (int*)alloc((size_t)NN * 4);
  int*   rowptr = (int*)alloc((size_t)(NN + 1) * 4);
  int*   fillptr= (int*)alloc((size_t)NN * 4);
  float* dinv   = (float*)alloc((size_t)NN * 4);
  int2*  edges  = (int2*)alloc((size_t)EE * 8);
  int*   blockSums = (int*)alloc(256 * 4);
  int*   blockOffs = (int*)alloc(256 * 4);
  float* gsum   = (float*)alloc((NGR * 6 + NGR) * 4);
  int*   gcnt   = (int*)(gsum + NGR * 6);

  hipMemsetAsync(counts, 0, (size_t)NN * 4, stream);
  hipMemsetAsync(gsum, 0, (NGR * 6 + NGR) * 4, stream);

  // CSR build (reused for all 3 layers)
  count_deg<<<(EE + 255) / 256, 256, 0, stream>>>(dst, counts);
  scan_block_sums<<<NB, 256, 0, stream>>>(counts, blockSums);
  scan_offsets<<<1, 256, 0, stream>>>(blockSums, blockOffs);
  scan_final<<<NB, 256, 0, stream>>>(counts, blockOffs, rowptr, fillptr, dinv);
  fill_csr<<<(EE + 255) / 256, 256, 0, stream>>>(src, dst, dinv, fillptr, edges);

  const int gemmGrid = (NN + 31) / 32;
  const int aggGrid  = (NN + 3) / 4;

  // layer 0: x -> bufA (h) -> bufB (act)
  gemm128<<<gemmGrid, 256, 0, stream>>>(x, W0, bufA);
  gcn_agg<<<aggGrid, 256, 0, stream>>>(bufA, rowptr, edges, dinv, b0, bufB);
  // layer 1
  gemm128<<<gemmGrid, 256, 0, stream>>>(bufB, W1, bufA);
  gcn_agg<<<aggGrid, 256, 0, stream>>>(bufA, rowptr, edges, dinv, b1, bufB);
  // layer 2
  gemm128<<<gemmGrid, 256, 0, stream>>>(bufB, W2, bufA);
  gcn_agg<<<aggGrid, 256, 0, stream>>>(bufA, rowptr, edges, dinv, b2, bufB);

  // final linear + tanh + mean pool
  linpool<<<(NN * 4 + 255) / 256, 256, 0, stream>>>(bufB, Wl, bl, batch, gsum, gcnt);
  finalize<<<1, NGR * 6, 0, stream>>>(gsum, gcnt, out);
}